// Round 9
// baseline (207.857 us; speedup 1.0000x reference)
//
#include <hip/hip_runtime.h>

#define L_DIM 4096
#define C_DIM 256
#define B_DIM 4
#define NH 8
#define DK 32

// Folds softmax 1/sqrt(DK) AND log2(e) into Wq at staging time, so the
// attention kernel uses a single v_exp_f32 (exp2) per score.
#define QSCALE 0.25507694f   // (1/sqrt(32)) * log2(e)

typedef __bf16 bf16x8 __attribute__((ext_vector_type(8)));
typedef float  f32x4  __attribute__((ext_vector_type(4)));
typedef float  f32x8  __attribute__((ext_vector_type(8)));
typedef float  f32x16 __attribute__((ext_vector_type(16)));

// pack two f32 -> packed bf16 pair (round-to-nearest via +0x8000, then
// byte-perm). Correct nearest-rounding for finite sign-magnitude values.
static __device__ __forceinline__ unsigned pk_bf16(float lo, float hi) {
    unsigned a = __builtin_bit_cast(unsigned, lo) + 0x8000u;
    unsigned b = __builtin_bit_cast(unsigned, hi) + 0x8000u;
    return __builtin_amdgcn_perm(b, a, 0x07060302u);   // {b[31:16], a[31:16]}
}

// ---------------------------------------------------------------------------
// Kernel 0: x [B,C,L] fp32 -> xt [B,L,C] bf16 (tiled transpose through LDS).
// ---------------------------------------------------------------------------
__global__ __launch_bounds__(256) void transpose_x_kernel(
    const float* __restrict__ x, __bf16* __restrict__ xt)
{
    const int t  = threadIdx.x;
    const int l0 = blockIdx.x * 64;
    const int c0 = blockIdx.y * 64;
    const int b  = blockIdx.z;

    __shared__ __attribute__((aligned(16))) float T[64][65];

    {
        const int r  = t >> 2;
        const int lc = (t & 3) * 16;
        const float* xp = x + ((size_t)b * C_DIM + c0 + r) * L_DIM + l0 + lc;
        #pragma unroll
        for (int k = 0; k < 4; ++k)
            *(f32x4*)&T[r][lc + k * 4] = *(const f32x4*)(xp + k * 4);
    }
    __syncthreads();
    {
        const int l  = t >> 2;
        const int cc = (t & 3) * 16;
        unsigned u[8];
        #pragma unroll
        for (int i = 0; i < 8; ++i)
            u[i] = pk_bf16(T[cc + 2 * i][l], T[cc + 2 * i + 1][l]);
        __bf16* op = xt + ((size_t)b * L_DIM + l0 + l) * C_DIM + c0 + cc;
        *(uint4*)op       = make_uint4(u[0], u[1], u[2], u[3]);
        *(uint4*)(op + 8) = make_uint4(u[4], u[5], u[6], u[7]);
    }
}

// ---------------------------------------------------------------------------
// Kernel 1: Q/K/V projections as bf16 MFMA GEMM (R4 version: fp32 W fetch,
// pk_bf16 conversion folded into staging).
// ---------------------------------------------------------------------------
__global__ __launch_bounds__(256) void proj_mfma_kernel(
    const __bf16* __restrict__ xt, const float* __restrict__ Wq,
    const float* __restrict__ Wk, const float* __restrict__ Wv,
    __bf16* __restrict__ Qb, __bf16* __restrict__ Kb, __bf16* __restrict__ Vb)
{
    const int t    = threadIdx.x;
    const int wave = t >> 6;
    const int lane = t & 63;
    const int n32  = lane & 31;
    const int hl   = lane >> 5;
    const int l0   = blockIdx.x * 128;
    const int ob   = blockIdx.y & 1;
    const int p    = blockIdx.y >> 1;   // 0=Q 1=K 2=V
    const int b    = blockIdx.z;
    const float* W = (p == 0) ? Wq : ((p == 1) ? Wk : Wv);
    const float sc = (p == 0) ? QSCALE : 1.0f;

    __shared__ __attribute__((aligned(16))) __bf16 Wt[128][72];  // [o][c]
    __shared__ __attribute__((aligned(16))) __bf16 Xs[128][72];  // [l][c]

    const int wo  = t >> 1, wcc = (t & 1) * 32;
    const int xl  = t >> 1, xcc = (t & 1) * 32;
    const float*  wg = W + (size_t)(ob * 128 + wo) * C_DIM + wcc;
    const __bf16* xg = xt + ((size_t)b * L_DIM + l0 + xl) * C_DIM + xcc;

    const int moff = (wave & 1) * 64;
    const int noff = (wave >> 1) * 64;

    f32x16 acc[2][2];
    #pragma unroll
    for (int i = 0; i < 2; ++i)
        #pragma unroll
        for (int j = 0; j < 2; ++j)
            #pragma unroll
            for (int r = 0; r < 16; ++r) acc[i][j][r] = 0.f;

    unsigned wpk[16];
    bf16x8   xpr[4];
    #pragma unroll
    for (int k = 0; k < 8; ++k) {
        f32x4 wv = *(const f32x4*)(wg + k * 4);
        wpk[k * 2]     = pk_bf16(wv[0] * sc, wv[1] * sc);
        wpk[k * 2 + 1] = pk_bf16(wv[2] * sc, wv[3] * sc);
    }
    #pragma unroll
    for (int g = 0; g < 4; ++g) xpr[g] = *(const bf16x8*)(xg + g * 8);

    for (int bk = 0; bk < 4; ++bk) {
        __syncthreads();
        #pragma unroll
        for (int g = 0; g < 4; ++g) {
            *(uint4*)&Wt[wo][wcc + g * 8] =
                make_uint4(wpk[g*4], wpk[g*4+1], wpk[g*4+2], wpk[g*4+3]);
            *(bf16x8*)&Xs[xl][xcc + g * 8] = xpr[g];
        }
        if (bk < 3) {
            #pragma unroll
            for (int k = 0; k < 8; ++k) {
                f32x4 wv = *(const f32x4*)(wg + (bk + 1) * 64 + k * 4);
                wpk[k * 2]     = pk_bf16(wv[0] * sc, wv[1] * sc);
                wpk[k * 2 + 1] = pk_bf16(wv[2] * sc, wv[3] * sc);
            }
            #pragma unroll
            for (int g = 0; g < 4; ++g)
                xpr[g] = *(const bf16x8*)(xg + (bk + 1) * 64 + g * 8);
        }
        __syncthreads();

        #pragma unroll
        for (int ks = 0; ks < 4; ++ks) {
            bf16x8 a0 = *(const bf16x8*)&Wt[moff + n32     ][ks * 16 + hl * 8];
            bf16x8 a1 = *(const bf16x8*)&Wt[moff + 32 + n32][ks * 16 + hl * 8];
            bf16x8 b0 = *(const bf16x8*)&Xs[noff + n32     ][ks * 16 + hl * 8];
            bf16x8 b1 = *(const bf16x8*)&Xs[noff + 32 + n32][ks * 16 + hl * 8];
            acc[0][0] = __builtin_amdgcn_mfma_f32_32x32x16_bf16(a0, b0, acc[0][0], 0, 0, 0);
            acc[0][1] = __builtin_amdgcn_mfma_f32_32x32x16_bf16(a0, b1, acc[0][1], 0, 0, 0);
            acc[1][0] = __builtin_amdgcn_mfma_f32_32x32x16_bf16(a1, b0, acc[1][0], 0, 0, 0);
            acc[1][1] = __builtin_amdgcn_mfma_f32_32x32x16_bf16(a1, b1, acc[1][1], 0, 0, 0);
        }
    }

    #pragma unroll
    for (int mt = 0; mt < 2; ++mt) {
        const int o32 = ob * 128 + moff + mt * 32;
        const int h   = o32 >> 5;
        const int bh  = b * NH + h;
        #pragma unroll
        for (int nt = 0; nt < 2; ++nt) {
            const int l = l0 + noff + nt * 32 + n32;
            if (p < 2) {
                __bf16* out = ((p == 0) ? Qb : Kb) + ((size_t)bh * L_DIM + l) * DK;
                #pragma unroll
                for (int g = 0; g < 4; ++g) {
                    unsigned u0 = pk_bf16(acc[mt][nt][g*4],     acc[mt][nt][g*4+1]);
                    unsigned u1 = pk_bf16(acc[mt][nt][g*4+2],   acc[mt][nt][g*4+3]);
                    *(uint2*)(out + 4 * hl + 8 * g) = make_uint2(u0, u1);
                }
            } else {
                #pragma unroll
                for (int r = 0; r < 16; ++r) {
                    const int dk = (r & 3) + 4 * hl + 8 * (r >> 2);
                    Vb[((size_t)bh * DK + dk) * L_DIM + l] = (__bf16)acc[mt][nt][r];
                }
            }
        }
    }
}

// ---------------------------------------------------------------------------
// Kernel 2: flash attention, K-SPLIT x2, KVBLK=128, double-buffered LDS,
// T14 async-STAGE split. Change this round: FOLDED-DENOMINATOR — instead of
// one mfma(ones, p) per P half (16 lacc MFMA/kt, 1/3 of matrix-pipe work),
// the e-vectors are summed in f32 (esum += e0+e1, placed BETWEEN exp and
// cvt so e0/e1 liveness is unchanged) and ONE mfma(ones, cvt(esum)) per
// (qt, half) accumulates the same column sums: 4 lacc MFMA/kt, -25% MFMA.
// esum lives only within a compute half, never across the staging section.
// ---------------------------------------------------------------------------
#define SCORE_TILE(K0, K1, V0, V1)                                            \
    _Pragma("unroll")                                                         \
    for (int qt = 0; qt < 2; ++qt) {                                          \
        f32x16 s = __builtin_amdgcn_mfma_f32_32x32x16_bf16(                   \
            K0, qf[qt][0], z16, 0, 0, 0);                                     \
        s = __builtin_amdgcn_mfma_f32_32x32x16_bf16(K1, qf[qt][1], s, 0, 0, 0); \
        f32x8 e0, e1;                                                         \
        _Pragma("unroll")                                                     \
        for (int r = 0; r < 8; ++r) {                                         \
            e0[r] = __builtin_amdgcn_exp2f(s[r]);                             \
            e1[r] = __builtin_amdgcn_exp2f(s[8 + r]);                         \
        }                                                                     \
        esum[qt] += e0 + e1;                                                  \
        bf16x8 p0 = __builtin_convertvector(e0, bf16x8);                      \
        bf16x8 p1 = __builtin_convertvector(e1, bf16x8);                      \
        oacc[qt] = __builtin_amdgcn_mfma_f32_32x32x16_bf16(                   \
            V0, p0, oacc[qt], 0, 0, 0);                                       \
        oacc[qt] = __builtin_amdgcn_mfma_f32_32x32x16_bf16(                   \
            V1, p1, oacc[qt], 0, 0, 0);                                       \
    }

#define LACC_FOLD()                                                           \
    _Pragma("unroll")                                                         \
    for (int qt = 0; qt < 2; ++qt) {                                          \
        bf16x8 pe = __builtin_convertvector(esum[qt], bf16x8);                \
        lacc[qt] = __builtin_amdgcn_mfma_f32_32x32x16_bf16(                   \
            ones, pe, lacc[qt], 0, 0, 0);                                     \
    }

__global__ __launch_bounds__(256) void attn_kernel(
    const __bf16* __restrict__ Q, const __bf16* __restrict__ K,
    const __bf16* __restrict__ V, __bf16* __restrict__ Op0,
    __bf16* __restrict__ Op1, float* __restrict__ Ls)
{
    const int tid   = threadIdx.x;
    const int lane  = tid & 63;
    const int n32   = lane & 31;
    const int hl    = lane >> 5;
    const int wave  = tid >> 6;
    const int h     = blockIdx.y;
    const int b     = blockIdx.z >> 1;
    const int khalf = blockIdx.z & 1;
    const int bh    = b * NH + h;
    const int q0    = blockIdx.x * 256 + wave * 64;

    __shared__ __attribute__((aligned(16))) __bf16 Ks[2][128][40];
    __shared__ __attribute__((aligned(16))) __bf16 Vs[2][32][136];

    bf16x8 qf[2][2];
    #pragma unroll
    for (int qt = 0; qt < 2; ++qt) {
        const __bf16* qp = Q + ((size_t)bh * L_DIM + q0 + qt * 32 + n32) * DK;
        qf[qt][0] = *(const bf16x8*)(qp + hl * 8);
        qf[qt][1] = *(const bf16x8*)(qp + 16 + hl * 8);
    }

    f32x16 oacc[2], lacc[2];
    #pragma unroll
    for (int qt = 0; qt < 2; ++qt)
        #pragma unroll
        for (int r = 0; r < 16; ++r) { oacc[qt][r] = 0.f; lacc[qt][r] = 0.f; }

    const f32x16 z16 = {};

    bf16x8 ones;
    #pragma unroll
    for (int j = 0; j < 8; ++j) ones[j] = (__bf16)1.0f;

    // staging addresses: 128 kpos/tile, 32B (2x bf16x8) per thread.
    const __bf16* kg = K + (size_t)bh * L_DIM * DK + (size_t)khalf * 2048 * DK
                         + (tid >> 1) * DK + (tid & 1) * 16;
    const __bf16* vg = V + ((size_t)bh * DK + (tid >> 3)) * L_DIM
                         + khalf * 2048 + (tid & 7) * 16;
    const int kr = tid >> 1, kc = (tid & 1) * 16;
    const int j16 = (tid & 7) * 16;   // V dest group base col
    const int vr  = tid >> 3;

    // prologue: stage tile 0 into buf0, prefetch tile 1 into regs
    bf16x8 kreg0 = *(const bf16x8*)(kg);
    bf16x8 kreg1 = *(const bf16x8*)(kg + 8);
    bf16x8 vreg0 = *(const bf16x8*)(vg);
    bf16x8 vreg1 = *(const bf16x8*)(vg + 8);
    {
        *(bf16x8*)&Ks[0][kr][kc]     = kreg0;
        *(bf16x8*)&Ks[0][kr][kc + 8] = kreg1;
        union { bf16x8 v; uint2 u2[2]; } v0, v1;
        v0.v = vreg0; v1.v = vreg1;
        *(uint2*)&Vs[0][vr][j16]      = v0.u2[0];   // kpos g 0-3
        *(uint2*)&Vs[0][vr][j16 + 8]  = v0.u2[1];   // kpos g 4-7
        *(uint2*)&Vs[0][vr][j16 + 4]  = v1.u2[0];   // kpos g 8-11
        *(uint2*)&Vs[0][vr][j16 + 12] = v1.u2[1];   // kpos g 12-15
    }
    kreg0 = *(const bf16x8*)(kg + (size_t)1 * 128 * DK);
    kreg1 = *(const bf16x8*)(kg + (size_t)1 * 128 * DK + 8);
    vreg0 = *(const bf16x8*)(vg + 128);
    vreg1 = *(const bf16x8*)(vg + 128 + 8);

    #pragma unroll 2
    for (int kt = 0; kt < 16; ++kt) {
        const int cur = kt & 1;
        __syncthreads();   // buf[cur] (tile kt) staged; prior reads of buf[cur^1] done

        // ---- first half fragments (mt 0,1) ----
        bf16x8 kA0 = *(const bf16x8*)&Ks[cur][n32     ][hl * 8];
        bf16x8 kA1 = *(const bf16x8*)&Ks[cur][n32     ][16 + hl * 8];
        bf16x8 kB0 = *(const bf16x8*)&Ks[cur][32 + n32][hl * 8];
        bf16x8 kB1 = *(const bf16x8*)&Ks[cur][32 + n32][16 + hl * 8];
        bf16x8 vA0 = *(const bf16x8*)&Vs[cur][n32][     hl * 8];
        bf16x8 vA1 = *(const bf16x8*)&Vs[cur][n32][16 + hl * 8];
        bf16x8 vB0 = *(const bf16x8*)&Vs[cur][n32][32 + hl * 8];
        bf16x8 vB1 = *(const bf16x8*)&Vs[cur][n32][48 + hl * 8];

        __builtin_amdgcn_s_setprio(1);
        {
            f32x8 esum[2] = {};
            SCORE_TILE(kA0, kA1, vA0, vA1)   // mt=0
            SCORE_TILE(kB0, kB1, vB0, vB1)   // mt=1
            LACC_FOLD()
        }
        __builtin_amdgcn_s_setprio(0);

        // ---- second half fragments (mt 2,3) — read BEFORE writes so the
        // second compute half waits only on these reads (LDS FIFO) ----
        kA0 = *(const bf16x8*)&Ks[cur][64 + n32][hl * 8];
        kA1 = *(const bf16x8*)&Ks[cur][64 + n32][16 + hl * 8];
        kB0 = *(const bf16x8*)&Ks[cur][96 + n32][hl * 8];
        kB1 = *(const bf16x8*)&Ks[cur][96 + n32][16 + hl * 8];
        vA0 = *(const bf16x8*)&Vs[cur][n32][64 + hl * 8];
        vA1 = *(const bf16x8*)&Vs[cur][n32][80 + hl * 8];
        vB0 = *(const bf16x8*)&Vs[cur][n32][96 + hl * 8];
        vB1 = *(const bf16x8*)&Vs[cur][n32][112 + hl * 8];

        if (kt < 15) {
            // T14: write tile kt+1 into the other buffer NOW (drains under
            // the second compute half), then issue depth-2 prefetch.
            *(bf16x8*)&Ks[cur ^ 1][kr][kc]     = kreg0;
            *(bf16x8*)&Ks[cur ^ 1][kr][kc + 8] = kreg1;
            union { bf16x8 v; uint2 u2[2]; } v0, v1;
            v0.v = vreg0; v1.v = vreg1;
            *(uint2*)&Vs[cur ^ 1][vr][j16]      = v0.u2[0];
            *(uint2*)&Vs[cur ^ 1][vr][j16 + 8]  = v0.u2[1];
            *(uint2*)&Vs[cur ^ 1][vr][j16 + 4]  = v1.u2[0];
            *(uint2*)&Vs[cur ^ 1][vr][j16 + 12] = v1.u2[1];
            const int nkt = (kt + 2) & 15;   // wraps, discarded at end
            kreg0 = *(const bf16x8*)(kg + (size_t)nkt * 128 * DK);
            kreg1 = *(const bf16x8*)(kg + (size_t)nkt * 128 * DK + 8);
            vreg0 = *(const bf16x8*)(vg + nkt * 128);
            vreg1 = *(const bf16x8*)(vg + nkt * 128 + 8);
        }

        __builtin_amdgcn_s_setprio(1);
        {
            f32x8 esum[2] = {};
            SCORE_TILE(kA0, kA1, vA0, vA1)   // mt=2
            SCORE_TILE(kB0, kB1, vB0, vB1)   // mt=3
            LACC_FOLD()
        }
        __builtin_amdgcn_s_setprio(0);
    }

    // epilogue: unnormalized O-half -> Op[khalf] in [B,L,C] layout; lsum -> Ls
    __bf16* Op = khalf ? Op1 : Op0;
    #pragma unroll
    for (int qt = 0; qt < 2; ++qt) {
        const int l = q0 + qt * 32 + n32;
        __bf16* ap = Op + ((size_t)b * L_DIM + l) * C_DIM + h * 32 + 4 * hl;
        #pragma unroll
        for (int g = 0; g < 4; ++g) {
            *(uint2*)(ap + 8 * g) = make_uint2(
                pk_bf16(oacc[qt][g*4],     oacc[qt][g*4+1]),
                pk_bf16(oacc[qt][g*4+2],   oacc[qt][g*4+3]));
        }
        Ls[((size_t)khalf * B_DIM * NH + bh) * L_DIM + l] = lacc[qt][0];
    }
}

// ---------------------------------------------------------------------------
// Kernel 3: final projection as bf16 MFMA GEMM with the K-split combine
// fused into staging: at = relu((O1+O2)/(l1+l2)).
// ---------------------------------------------------------------------------
__global__ __launch_bounds__(256) void final_mfma_kernel(
    const __bf16* __restrict__ Op0, const __bf16* __restrict__ Op1,
    const float* __restrict__ Ls, const float* __restrict__ Wl,
    float* __restrict__ y)
{
    const int t    = threadIdx.x;
    const int wave = t >> 6;
    const int lane = t & 63;
    const int n32  = lane & 31;
    const int hl   = lane >> 5;
    const int l0   = blockIdx.x * 64;
    const int ob   = blockIdx.y;
    const int b    = blockIdx.z;

    __shared__ __attribute__((aligned(16))) __bf16 Wt[128][72];
    __shared__ __attribute__((aligned(16))) __bf16 Xs[64][72];

    const int wo  = t >> 1, wcc = (t & 1) * 32;
    const int xl  = t >> 2, xcc = (t & 3) * 16;
    const float* wg = Wl + (size_t)(ob * 128 + wo) * C_DIM + wcc;
    const size_t obase = ((size_t)b * L_DIM + l0 + xl) * C_DIM + xcc;

    // per-bk inverse denominators: head for chunk bk is bk*2 + (xcc>>5 within 64)
    float inv[4];
    {
        const int lidx = l0 + xl;
        #pragma unroll
        for (int bk = 0; bk < 4; ++bk) {
            const int hh = (bk * 64 + xcc) >> 5;
            const float l1 = Ls[((size_t)0 * B_DIM * NH + b * NH + hh) * L_DIM + lidx];
            const float l2 = Ls[((size_t)1 * B_DIM * NH + b * NH + hh) * L_DIM + lidx];
            inv[bk] = __builtin_amdgcn_rcpf(l1 + l2);
        }
    }

    const int moff = (wave & 1) * 64;
    const int noff = (wave >> 1) * 32;

    f32x16 acc[2];
    #pragma unroll
    for (int i = 0; i < 2; ++i)
        #pragma unroll
        for (int r = 0; r < 16; ++r) acc[i][r] = 0.f;

    unsigned wpk[16];
    bf16x8   o1r, o2r;
    #pragma unroll
    for (int k = 0; k < 8; ++k) {
        f32x4 wv = *(const f32x4*)(wg + k * 4);
        wpk[k * 2]     = pk_bf16(wv[0], wv[1]);
        wpk[k * 2 + 1] = pk_bf16(wv[2], wv[3]);
    }
    o1r = *(const bf16x8*)(Op0 + obase);
    o2r = *(const bf16x8*)(Op1 + obase);
    bf16x8 o1r2 = *(const bf16x8*)(Op0 + obase + 8);
    bf16x8 o2r2 = *(const bf16x8*)(Op1 + obase + 8);

    for (int bk = 0; bk < 4; ++bk) {
        __syncthreads();
        #pragma unroll
        for (int g = 0; g < 4; ++g)
            *(uint4*)&Wt[wo][wcc + g * 8] =
                make_uint4(wpk[g*4], wpk[g*4+1], wpk[g*4+2], wpk[g*4+3]);
        {   // combine halves: relu((O1+O2)*inv) -> bf16 fragment row
            unsigned u[4];
            #pragma unroll
            for (int i = 0; i < 4; ++i) {
                float v0 = ((float)o1r[2*i]   + (float)o2r[2*i]  ) * inv[bk];
                float v1 = ((float)o1r[2*i+1] + (float)o2r[2*i+1]) * inv[bk];
                v0 = v0 > 0.f ? v0 : 0.f;
                v1 = v1 > 0.f ? v1 : 0.f;
                u[i] = pk_bf16(v0, v1);
            }
            *(uint4*)&Xs[xl][xcc] = make_uint4(u[0], u[1], u[2], u[3]);
            #pragma unroll
            for (int i = 0; i < 4; ++i) {
                float v0 = ((float)o1r2[2*i]   + (float)o2r2[2*i]  ) * inv[bk];
                float v1 = ((float)o1r2[2*i+1] + (float)o2r2[2*i+1]) * inv[bk];
                v0 = v0 > 0.f ? v0 : 0.f;
                v1 = v1 > 0.f ? v1 : 0.f;
                u[i] = pk_bf16(v0, v1);
            }
            *(uint4*)&Xs[xl][xcc + 8] = make_uint4(u[0], u[1], u[2], u[3]);
        }
        if (bk < 3) {
            #pragma unroll
            for (int k = 0; k < 8; ++k) {
                f32x4 wv = *(const f32x4*)(wg + (bk + 1) * 64 + k * 4);
                wpk[k * 2]     = pk_bf16(wv[0], wv[1]);
                wpk[k * 2 + 1] = pk_bf16(wv[2], wv[3]);
            }
            o1r  = *(const bf16x8*)(Op0 + obase + (bk + 1) * 64);
            o2r  = *(const bf16x8*)(Op1 + obase + (bk + 1) * 64);
            o1r2 = *(const bf16x8*)(Op0 + obase + (bk + 1) * 64 + 8);
            o2r2 = *(const bf16x8*)(Op1 + obase + (bk + 1) * 64 + 8);
        }
        __syncthreads();

        #pragma unroll
        for (int ks = 0; ks < 4; ++ks) {
            bf16x8 a0 = *(const bf16x8*)&Wt[moff + n32     ][ks * 16 + hl * 8];
            bf16x8 a1 = *(const bf16x8*)&Wt[moff + 32 + n32][ks * 16 + hl * 8];
            bf16x8 b0 = *(const bf16x8*)&Xs[noff + n32     ][ks * 16 + hl * 8];
            acc[0] = __builtin_amdgcn_mfma_f32_32x32x16_bf16(a0, b0, acc[0], 0, 0, 0);
            acc[1] = __builtin_amdgcn_mfma_f32_32x32x16_bf16(a1, b0, acc[1], 0, 0, 0);
        }
    }

    #pragma unroll
    for (int mt = 0; mt < 2; ++mt) {
        #pragma unroll
        for (int r = 0; r < 16; ++r) {
            const int o = ob * 128 + moff + mt * 32 + (r & 3) + 4 * hl + 8 * (r >> 2);
            y[((size_t)b * C_DIM + o) * L_DIM + l0 + noff + n32] = acc[mt][r];
        }
    }
}

// ---------------------------------------------------------------------------
extern "C" void kernel_launch(void* const* d_in, const int* in_sizes, int n_in,
                              void* d_out, int out_size, void* d_ws, size_t ws_size,
                              hipStream_t stream)
{
    const float* x  = (const float*)d_in[0];
    const float* Wq = (const float*)d_in[1];
    const float* Wk = (const float*)d_in[2];
    const float* Wv = (const float*)d_in[3];
    const float* Wl = (const float*)d_in[4];
    float* y = (float*)d_out;

    const size_t n = (size_t)B_DIM * NH * L_DIM * DK;   // 4,194,304 elems
    __bf16* Qb  = (__bf16*)d_ws;          // [B,H,L,DK]
    __bf16* Kb  = Qb + n;
    __bf16* Vb  = Kb + n;                 // [B,H,DK,L]
    __bf16* Xt  = Vb + n;                 // [B,L,C]; dead after proj
    __bf16* Op0 = Xt;                     // aliases Xt: O-half 0, [B,L,C]
    __bf16* Op1 = Xt + n;                 // O-half 1
    float*  Ls  = (float*)(Op1 + n);      // [2][B*NH][L] exp-sums

    transpose_x_kernel<<<dim3(L_DIM/64, C_DIM/64, B_DIM), 256, 0, stream>>>(x, Xt);
    proj_mfma_kernel<<<dim3(L_DIM/128, 6, B_DIM), 256, 0, stream>>>(
        Xt, Wq, Wk, Wv, Qb, Kb, Vb);
    attn_kernel<<<dim3(L_DIM/256, NH, B_DIM * 2), 256, 0, stream>>>(
        Qb, Kb, Vb, Op0, Op1, Ls);
    final_mfma_kernel<<<dim3(L_DIM/64, 2, B_DIM), 256, 0, stream>>>(
        Op0, Op1, Ls, Wl, y);
}

// Round 10
// 205.900 us; speedup vs baseline: 1.0095x; 1.0095x over previous
//
#include <hip/hip_runtime.h>

#define L_DIM 4096
#define C_DIM 256
#define B_DIM 4
#define NH 8
#define DK 32

// Folds softmax 1/sqrt(DK) AND log2(e) into Wq at staging time, so the
// attention kernel uses a single v_exp_f32 (exp2) per score.
#define QSCALE 0.25507694f   // (1/sqrt(32)) * log2(e)

typedef __bf16 bf16x8 __attribute__((ext_vector_type(8)));
typedef float  f32x4  __attribute__((ext_vector_type(4)));
typedef float  f32x8  __attribute__((ext_vector_type(8)));
typedef float  f32x16 __attribute__((ext_vector_type(16)));

// pack two f32 -> packed bf16 pair (round-to-nearest via +0x8000, then
// byte-perm). Correct nearest-rounding for finite sign-magnitude values.
static __device__ __forceinline__ unsigned pk_bf16(float lo, float hi) {
    unsigned a = __builtin_bit_cast(unsigned, lo) + 0x8000u;
    unsigned b = __builtin_bit_cast(unsigned, hi) + 0x8000u;
    return __builtin_amdgcn_perm(b, a, 0x07060302u);   // {b[31:16], a[31:16]}
}

// ---------------------------------------------------------------------------
// Kernel 1: Q/K/V projections as bf16 MFMA GEMM, with the x-transpose FUSED
// into staging (kernel 0 eliminated). Each thread loads a 4c x 8l fp32
// micro-tile straight from x [B,C,L] (coalesced: 16 lanes x 32B contiguous
// per c-row), packs c-pairs to bf16 in-register, writes Xs directly.
// LDS write conflicts (8-row stride = 0 mod 32 banks) fixed by XOR swizzle
// col ^= ((row>>3)&7)*8, applied identically on fragment reads.
// ---------------------------------------------------------------------------
__global__ __launch_bounds__(256) void proj_mfma_kernel(
    const float* __restrict__ x, const float* __restrict__ Wq,
    const float* __restrict__ Wk, const float* __restrict__ Wv,
    __bf16* __restrict__ Qb, __bf16* __restrict__ Kb, __bf16* __restrict__ Vb)
{
    const int t    = threadIdx.x;
    const int wave = t >> 6;
    const int lane = t & 63;
    const int n32  = lane & 31;
    const int hl   = lane >> 5;
    const int l0   = blockIdx.x * 128;
    const int ob   = blockIdx.y & 1;
    const int p    = blockIdx.y >> 1;   // 0=Q 1=K 2=V
    const int b    = blockIdx.z;
    const float* W = (p == 0) ? Wq : ((p == 1) ? Wk : Wv);
    const float sc = (p == 0) ? QSCALE : 1.0f;

    __shared__ __attribute__((aligned(16))) __bf16 Wt[128][72];  // [o][c]
    __shared__ __attribute__((aligned(16))) __bf16 Xs[128][72];  // [l][c] swz

    const int wo  = t >> 1, wcc = (t & 1) * 32;
    const float* wg = W + (size_t)(ob * 128 + wo) * C_DIM + wcc;

    // x-stage geometry: thread covers c = bk*64 + cg*4 .. +3, l = lq*8 .. +7
    const int lq  = t & 15;
    const int cg  = t >> 4;
    const int swW = (lq & 7) * 8;   // write swizzle: rows lq*8+j have row>>3 == lq
    const float* xg = x + ((size_t)b * C_DIM + cg * 4) * L_DIM + l0 + lq * 8;

    const int moff = (wave & 1) * 64;
    const int noff = (wave >> 1) * 64;
    const int sw0  = ((n32 >> 3) & 7) * 8;        // read swizzle, rows noff+n32
    const int sw1  = ((4 + (n32 >> 3)) & 7) * 8;  // rows noff+32+n32

    f32x16 acc[2][2];
    #pragma unroll
    for (int i = 0; i < 2; ++i)
        #pragma unroll
        for (int j = 0; j < 2; ++j)
            #pragma unroll
            for (int r = 0; r < 16; ++r) acc[i][j][r] = 0.f;

    unsigned wpk[16];
    unsigned ux[16];

#define XSTAGE_LOAD(bkk)                                                      \
    {                                                                         \
        const float* xp = xg + (size_t)(bkk) * 64 * L_DIM;                    \
        f32x8 r0 = *(const f32x8*)(xp);                                       \
        f32x8 r1 = *(const f32x8*)(xp + L_DIM);                               \
        _Pragma("unroll")                                                     \
        for (int j = 0; j < 8; ++j) ux[j] = pk_bf16(r0[j], r1[j]);            \
        f32x8 r2 = *(const f32x8*)(xp + 2 * L_DIM);                           \
        f32x8 r3 = *(const f32x8*)(xp + 3 * L_DIM);                           \
        _Pragma("unroll")                                                     \
        for (int j = 0; j < 8; ++j) ux[8 + j] = pk_bf16(r2[j], r3[j]);        \
    }

    #pragma unroll
    for (int k = 0; k < 8; ++k) {
        f32x4 wv = *(const f32x4*)(wg + k * 4);
        wpk[k * 2]     = pk_bf16(wv[0] * sc, wv[1] * sc);
        wpk[k * 2 + 1] = pk_bf16(wv[2] * sc, wv[3] * sc);
    }
    XSTAGE_LOAD(0)

    for (int bk = 0; bk < 4; ++bk) {
        __syncthreads();
        #pragma unroll
        for (int g = 0; g < 4; ++g)
            *(uint4*)&Wt[wo][wcc + g * 8] =
                make_uint4(wpk[g*4], wpk[g*4+1], wpk[g*4+2], wpk[g*4+3]);
        #pragma unroll
        for (int j = 0; j < 8; ++j)
            *(uint2*)&Xs[lq * 8 + j][(cg * 4) ^ swW] = make_uint2(ux[j], ux[8 + j]);
        if (bk < 3) {
            #pragma unroll
            for (int k = 0; k < 8; ++k) {
                f32x4 wv = *(const f32x4*)(wg + (bk + 1) * 64 + k * 4);
                wpk[k * 2]     = pk_bf16(wv[0] * sc, wv[1] * sc);
                wpk[k * 2 + 1] = pk_bf16(wv[2] * sc, wv[3] * sc);
            }
            XSTAGE_LOAD(bk + 1)
        }
        __syncthreads();

        #pragma unroll
        for (int ks = 0; ks < 4; ++ks) {
            bf16x8 a0 = *(const bf16x8*)&Wt[moff + n32     ][ks * 16 + hl * 8];
            bf16x8 a1 = *(const bf16x8*)&Wt[moff + 32 + n32][ks * 16 + hl * 8];
            bf16x8 b0 = *(const bf16x8*)&Xs[noff + n32     ][(ks * 16 + hl * 8) ^ sw0];
            bf16x8 b1 = *(const bf16x8*)&Xs[noff + 32 + n32][(ks * 16 + hl * 8) ^ sw1];
            acc[0][0] = __builtin_amdgcn_mfma_f32_32x32x16_bf16(a0, b0, acc[0][0], 0, 0, 0);
            acc[0][1] = __builtin_amdgcn_mfma_f32_32x32x16_bf16(a0, b1, acc[0][1], 0, 0, 0);
            acc[1][0] = __builtin_amdgcn_mfma_f32_32x32x16_bf16(a1, b0, acc[1][0], 0, 0, 0);
            acc[1][1] = __builtin_amdgcn_mfma_f32_32x32x16_bf16(a1, b1, acc[1][1], 0, 0, 0);
        }
    }
#undef XSTAGE_LOAD

    #pragma unroll
    for (int mt = 0; mt < 2; ++mt) {
        const int o32 = ob * 128 + moff + mt * 32;
        const int h   = o32 >> 5;
        const int bh  = b * NH + h;
        #pragma unroll
        for (int nt = 0; nt < 2; ++nt) {
            const int l = l0 + noff + nt * 32 + n32;
            if (p < 2) {
                __bf16* out = ((p == 0) ? Qb : Kb) + ((size_t)bh * L_DIM + l) * DK;
                #pragma unroll
                for (int g = 0; g < 4; ++g) {
                    unsigned u0 = pk_bf16(acc[mt][nt][g*4],     acc[mt][nt][g*4+1]);
                    unsigned u1 = pk_bf16(acc[mt][nt][g*4+2],   acc[mt][nt][g*4+3]);
                    *(uint2*)(out + 4 * hl + 8 * g) = make_uint2(u0, u1);
                }
            } else {
                #pragma unroll
                for (int r = 0; r < 16; ++r) {
                    const int dk = (r & 3) + 4 * hl + 8 * (r >> 2);
                    Vb[((size_t)bh * DK + dk) * L_DIM + l] = (__bf16)acc[mt][nt][r];
                }
            }
        }
    }
}

// ---------------------------------------------------------------------------
// Kernel 2: flash attention, K-SPLIT x2, KVBLK=128, double-buffered LDS,
// T14 async-STAGE split, lacc denominator on the MFMA pipe (R8 attn — best
// measured 105.4 us). R9's folded denominator regressed: the lacc MFMAs
// were off-critical-path filler; removing them only lengthened the VALU
// chain. Do not touch the denominator again.
// ---------------------------------------------------------------------------
#define SCORE_TILE(K0, K1, V0, V1)                                            \
    _Pragma("unroll")                                                         \
    for (int qt = 0; qt < 2; ++qt) {                                          \
        f32x16 s = __builtin_amdgcn_mfma_f32_32x32x16_bf16(                   \
            K0, qf[qt][0], z16, 0, 0, 0);                                     \
        s = __builtin_amdgcn_mfma_f32_32x32x16_bf16(K1, qf[qt][1], s, 0, 0, 0); \
        f32x8 e0, e1;                                                         \
        _Pragma("unroll")                                                     \
        for (int r = 0; r < 8; ++r) {                                         \
            e0[r] = __builtin_amdgcn_exp2f(s[r]);                             \
            e1[r] = __builtin_amdgcn_exp2f(s[8 + r]);                         \
        }                                                                     \
        bf16x8 p0 = __builtin_convertvector(e0, bf16x8);                      \
        bf16x8 p1 = __builtin_convertvector(e1, bf16x8);                      \
        oacc[qt] = __builtin_amdgcn_mfma_f32_32x32x16_bf16(                   \
            V0, p0, oacc[qt], 0, 0, 0);                                       \
        lacc[qt] = __builtin_amdgcn_mfma_f32_32x32x16_bf16(                   \
            ones, p0, lacc[qt], 0, 0, 0);                                     \
        oacc[qt] = __builtin_amdgcn_mfma_f32_32x32x16_bf16(                   \
            V1, p1, oacc[qt], 0, 0, 0);                                       \
        lacc[qt] = __builtin_amdgcn_mfma_f32_32x32x16_bf16(                   \
            ones, p1, lacc[qt], 0, 0, 0);                                     \
    }

__global__ __launch_bounds__(256) void attn_kernel(
    const __bf16* __restrict__ Q, const __bf16* __restrict__ K,
    const __bf16* __restrict__ V, __bf16* __restrict__ Op0,
    __bf16* __restrict__ Op1, float* __restrict__ Ls)
{
    const int tid   = threadIdx.x;
    const int lane  = tid & 63;
    const int n32   = lane & 31;
    const int hl    = lane >> 5;
    const int wave  = tid >> 6;
    const int h     = blockIdx.y;
    const int b     = blockIdx.z >> 1;
    const int khalf = blockIdx.z & 1;
    const int bh    = b * NH + h;
    const int q0    = blockIdx.x * 256 + wave * 64;

    __shared__ __attribute__((aligned(16))) __bf16 Ks[2][128][40];
    __shared__ __attribute__((aligned(16))) __bf16 Vs[2][32][136];

    bf16x8 qf[2][2];
    #pragma unroll
    for (int qt = 0; qt < 2; ++qt) {
        const __bf16* qp = Q + ((size_t)bh * L_DIM + q0 + qt * 32 + n32) * DK;
        qf[qt][0] = *(const bf16x8*)(qp + hl * 8);
        qf[qt][1] = *(const bf16x8*)(qp + 16 + hl * 8);
    }

    f32x16 oacc[2], lacc[2];
    #pragma unroll
    for (int qt = 0; qt < 2; ++qt)
        #pragma unroll
        for (int r = 0; r < 16; ++r) { oacc[qt][r] = 0.f; lacc[qt][r] = 0.f; }

    const f32x16 z16 = {};

    bf16x8 ones;
    #pragma unroll
    for (int j = 0; j < 8; ++j) ones[j] = (__bf16)1.0f;

    // staging addresses: 128 kpos/tile, 32B (2x bf16x8) per thread.
    const __bf16* kg = K + (size_t)bh * L_DIM * DK + (size_t)khalf * 2048 * DK
                         + (tid >> 1) * DK + (tid & 1) * 16;
    const __bf16* vg = V + ((size_t)bh * DK + (tid >> 3)) * L_DIM
                         + khalf * 2048 + (tid & 7) * 16;
    const int kr = tid >> 1, kc = (tid & 1) * 16;
    const int j16 = (tid & 7) * 16;   // V dest group base col
    const int vr  = tid >> 3;

    // prologue: stage tile 0 into buf0, prefetch tile 1 into regs
    bf16x8 kreg0 = *(const bf16x8*)(kg);
    bf16x8 kreg1 = *(const bf16x8*)(kg + 8);
    bf16x8 vreg0 = *(const bf16x8*)(vg);
    bf16x8 vreg1 = *(const bf16x8*)(vg + 8);
    {
        *(bf16x8*)&Ks[0][kr][kc]     = kreg0;
        *(bf16x8*)&Ks[0][kr][kc + 8] = kreg1;
        union { bf16x8 v; uint2 u2[2]; } v0, v1;
        v0.v = vreg0; v1.v = vreg1;
        *(uint2*)&Vs[0][vr][j16]      = v0.u2[0];   // kpos g 0-3
        *(uint2*)&Vs[0][vr][j16 + 8]  = v0.u2[1];   // kpos g 4-7
        *(uint2*)&Vs[0][vr][j16 + 4]  = v1.u2[0];   // kpos g 8-11
        *(uint2*)&Vs[0][vr][j16 + 12] = v1.u2[1];   // kpos g 12-15
    }
    kreg0 = *(const bf16x8*)(kg + (size_t)1 * 128 * DK);
    kreg1 = *(const bf16x8*)(kg + (size_t)1 * 128 * DK + 8);
    vreg0 = *(const bf16x8*)(vg + 128);
    vreg1 = *(const bf16x8*)(vg + 128 + 8);

    #pragma unroll 2
    for (int kt = 0; kt < 16; ++kt) {
        const int cur = kt & 1;
        __syncthreads();   // buf[cur] (tile kt) staged; prior reads of buf[cur^1] done

        // ---- first half fragments (mt 0,1) ----
        bf16x8 kA0 = *(const bf16x8*)&Ks[cur][n32     ][hl * 8];
        bf16x8 kA1 = *(const bf16x8*)&Ks[cur][n32     ][16 + hl * 8];
        bf16x8 kB0 = *(const bf16x8*)&Ks[cur][32 + n32][hl * 8];
        bf16x8 kB1 = *(const bf16x8*)&Ks[cur][32 + n32][16 + hl * 8];
        bf16x8 vA0 = *(const bf16x8*)&Vs[cur][n32][     hl * 8];
        bf16x8 vA1 = *(const bf16x8*)&Vs[cur][n32][16 + hl * 8];
        bf16x8 vB0 = *(const bf16x8*)&Vs[cur][n32][32 + hl * 8];
        bf16x8 vB1 = *(const bf16x8*)&Vs[cur][n32][48 + hl * 8];

        __builtin_amdgcn_s_setprio(1);
        SCORE_TILE(kA0, kA1, vA0, vA1)   // mt=0
        SCORE_TILE(kB0, kB1, vB0, vB1)   // mt=1
        __builtin_amdgcn_s_setprio(0);

        // ---- second half fragments (mt 2,3) — read BEFORE writes so the
        // second compute half waits only on these reads (LDS FIFO) ----
        kA0 = *(const bf16x8*)&Ks[cur][64 + n32][hl * 8];
        kA1 = *(const bf16x8*)&Ks[cur][64 + n32][16 + hl * 8];
        kB0 = *(const bf16x8*)&Ks[cur][96 + n32][hl * 8];
        kB1 = *(const bf16x8*)&Ks[cur][96 + n32][16 + hl * 8];
        vA0 = *(const bf16x8*)&Vs[cur][n32][64 + hl * 8];
        vA1 = *(const bf16x8*)&Vs[cur][n32][80 + hl * 8];
        vB0 = *(const bf16x8*)&Vs[cur][n32][96 + hl * 8];
        vB1 = *(const bf16x8*)&Vs[cur][n32][112 + hl * 8];

        if (kt < 15) {
            // T14: write tile kt+1 into the other buffer NOW (drains under
            // the second compute half), then issue depth-2 prefetch.
            *(bf16x8*)&Ks[cur ^ 1][kr][kc]     = kreg0;
            *(bf16x8*)&Ks[cur ^ 1][kr][kc + 8] = kreg1;
            union { bf16x8 v; uint2 u2[2]; } v0, v1;
            v0.v = vreg0; v1.v = vreg1;
            *(uint2*)&Vs[cur ^ 1][vr][j16]      = v0.u2[0];
            *(uint2*)&Vs[cur ^ 1][vr][j16 + 8]  = v0.u2[1];
            *(uint2*)&Vs[cur ^ 1][vr][j16 + 4]  = v1.u2[0];
            *(uint2*)&Vs[cur ^ 1][vr][j16 + 12] = v1.u2[1];
            const int nkt = (kt + 2) & 15;   // wraps, discarded at end
            kreg0 = *(const bf16x8*)(kg + (size_t)nkt * 128 * DK);
            kreg1 = *(const bf16x8*)(kg + (size_t)nkt * 128 * DK + 8);
            vreg0 = *(const bf16x8*)(vg + nkt * 128);
            vreg1 = *(const bf16x8*)(vg + nkt * 128 + 8);
        }

        __builtin_amdgcn_s_setprio(1);
        SCORE_TILE(kA0, kA1, vA0, vA1)   // mt=2
        SCORE_TILE(kB0, kB1, vB0, vB1)   // mt=3
        __builtin_amdgcn_s_setprio(0);
    }

    // epilogue: unnormalized O-half -> Op[khalf] in [B,L,C] layout; lsum -> Ls
    __bf16* Op = khalf ? Op1 : Op0;
    #pragma unroll
    for (int qt = 0; qt < 2; ++qt) {
        const int l = q0 + qt * 32 + n32;
        __bf16* ap = Op + ((size_t)b * L_DIM + l) * C_DIM + h * 32 + 4 * hl;
        #pragma unroll
        for (int g = 0; g < 4; ++g) {
            *(uint2*)(ap + 8 * g) = make_uint2(
                pk_bf16(oacc[qt][g*4],     oacc[qt][g*4+1]),
                pk_bf16(oacc[qt][g*4+2],   oacc[qt][g*4+3]));
        }
        Ls[((size_t)khalf * B_DIM * NH + bh) * L_DIM + l] = lacc[qt][0];
    }
}

// ---------------------------------------------------------------------------
// Kernel 3: final projection as bf16 MFMA GEMM with the K-split combine
// fused into staging: at = relu((O1+O2)/(l1+l2)).
// ---------------------------------------------------------------------------
__global__ __launch_bounds__(256) void final_mfma_kernel(
    const __bf16* __restrict__ Op0, const __bf16* __restrict__ Op1,
    const float* __restrict__ Ls, const float* __restrict__ Wl,
    float* __restrict__ y)
{
    const int t    = threadIdx.x;
    const int wave = t >> 6;
    const int lane = t & 63;
    const int n32  = lane & 31;
    const int hl   = lane >> 5;
    const int l0   = blockIdx.x * 64;
    const int ob   = blockIdx.y;
    const int b    = blockIdx.z;

    __shared__ __attribute__((aligned(16))) __bf16 Wt[128][72];
    __shared__ __attribute__((aligned(16))) __bf16 Xs[64][72];

    const int wo  = t >> 1, wcc = (t & 1) * 32;
    const int xl  = t >> 2, xcc = (t & 3) * 16;
    const float* wg = Wl + (size_t)(ob * 128 + wo) * C_DIM + wcc;
    const size_t obase = ((size_t)b * L_DIM + l0 + xl) * C_DIM + xcc;

    // per-bk inverse denominators: head for chunk bk is bk*2 + (xcc>>5 within 64)
    float inv[4];
    {
        const int lidx = l0 + xl;
        #pragma unroll
        for (int bk = 0; bk < 4; ++bk) {
            const int hh = (bk * 64 + xcc) >> 5;
            const float l1 = Ls[((size_t)0 * B_DIM * NH + b * NH + hh) * L_DIM + lidx];
            const float l2 = Ls[((size_t)1 * B_DIM * NH + b * NH + hh) * L_DIM + lidx];
            inv[bk] = __builtin_amdgcn_rcpf(l1 + l2);
        }
    }

    const int moff = (wave & 1) * 64;
    const int noff = (wave >> 1) * 32;

    f32x16 acc[2];
    #pragma unroll
    for (int i = 0; i < 2; ++i)
        #pragma unroll
        for (int r = 0; r < 16; ++r) acc[i][r] = 0.f;

    unsigned wpk[16];
    bf16x8   o1r, o2r;
    #pragma unroll
    for (int k = 0; k < 8; ++k) {
        f32x4 wv = *(const f32x4*)(wg + k * 4);
        wpk[k * 2]     = pk_bf16(wv[0], wv[1]);
        wpk[k * 2 + 1] = pk_bf16(wv[2], wv[3]);
    }
    o1r = *(const bf16x8*)(Op0 + obase);
    o2r = *(const bf16x8*)(Op1 + obase);
    bf16x8 o1r2 = *(const bf16x8*)(Op0 + obase + 8);
    bf16x8 o2r2 = *(const bf16x8*)(Op1 + obase + 8);

    for (int bk = 0; bk < 4; ++bk) {
        __syncthreads();
        #pragma unroll
        for (int g = 0; g < 4; ++g)
            *(uint4*)&Wt[wo][wcc + g * 8] =
                make_uint4(wpk[g*4], wpk[g*4+1], wpk[g*4+2], wpk[g*4+3]);
        {   // combine halves: relu((O1+O2)*inv) -> bf16 fragment row
            unsigned u[4];
            #pragma unroll
            for (int i = 0; i < 4; ++i) {
                float v0 = ((float)o1r[2*i]   + (float)o2r[2*i]  ) * inv[bk];
                float v1 = ((float)o1r[2*i+1] + (float)o2r[2*i+1]) * inv[bk];
                v0 = v0 > 0.f ? v0 : 0.f;
                v1 = v1 > 0.f ? v1 : 0.f;
                u[i] = pk_bf16(v0, v1);
            }
            *(uint4*)&Xs[xl][xcc] = make_uint4(u[0], u[1], u[2], u[3]);
            #pragma unroll
            for (int i = 0; i < 4; ++i) {
                float v0 = ((float)o1r2[2*i]   + (float)o2r2[2*i]  ) * inv[bk];
                float v1 = ((float)o1r2[2*i+1] + (float)o2r2[2*i+1]) * inv[bk];
                v0 = v0 > 0.f ? v0 : 0.f;
                v1 = v1 > 0.f ? v1 : 0.f;
                u[i] = pk_bf16(v0, v1);
            }
            *(uint4*)&Xs[xl][xcc + 8] = make_uint4(u[0], u[1], u[2], u[3]);
        }
        if (bk < 3) {
            #pragma unroll
            for (int k = 0; k < 8; ++k) {
                f32x4 wv = *(const f32x4*)(wg + (bk + 1) * 64 + k * 4);
                wpk[k * 2]     = pk_bf16(wv[0], wv[1]);
                wpk[k * 2 + 1] = pk_bf16(wv[2], wv[3]);
            }
            o1r  = *(const bf16x8*)(Op0 + obase + (bk + 1) * 64);
            o2r  = *(const bf16x8*)(Op1 + obase + (bk + 1) * 64);
            o1r2 = *(const bf16x8*)(Op0 + obase + (bk + 1) * 64 + 8);
            o2r2 = *(const bf16x8*)(Op1 + obase + (bk + 1) * 64 + 8);
        }
        __syncthreads();

        #pragma unroll
        for (int ks = 0; ks < 4; ++ks) {
            bf16x8 a0 = *(const bf16x8*)&Wt[moff + n32     ][ks * 16 + hl * 8];
            bf16x8 a1 = *(const bf16x8*)&Wt[moff + 32 + n32][ks * 16 + hl * 8];
            bf16x8 b0 = *(const bf16x8*)&Xs[noff + n32     ][ks * 16 + hl * 8];
            acc[0] = __builtin_amdgcn_mfma_f32_32x32x16_bf16(a0, b0, acc[0], 0, 0, 0);
            acc[1] = __builtin_amdgcn_mfma_f32_32x32x16_bf16(a1, b0, acc[1], 0, 0, 0);
        }
    }

    #pragma unroll
    for (int mt = 0; mt < 2; ++mt) {
        #pragma unroll
        for (int r = 0; r < 16; ++r) {
            const int o = ob * 128 + moff + mt * 32 + (r & 3) + 4 * hl + 8 * (r >> 2);
            y[((size_t)b * C_DIM + o) * L_DIM + l0 + noff + n32] = acc[mt][r];
        }
    }
}

// ---------------------------------------------------------------------------
extern "C" void kernel_launch(void* const* d_in, const int* in_sizes, int n_in,
                              void* d_out, int out_size, void* d_ws, size_t ws_size,
                              hipStream_t stream)
{
    const float* x  = (const float*)d_in[0];
    const float* Wq = (const float*)d_in[1];
    const float* Wk = (const float*)d_in[2];
    const float* Wv = (const float*)d_in[3];
    const float* Wl = (const float*)d_in[4];
    float* y = (float*)d_out;

    const size_t n = (size_t)B_DIM * NH * L_DIM * DK;   // 4,194,304 elems
    __bf16* Qb  = (__bf16*)d_ws;          // [B,H,L,DK]
    __bf16* Kb  = Qb + n;
    __bf16* Vb  = Kb + n;                 // [B,H,DK,L]
    __bf16* Op0 = Vb + n;                 // O-half 0, [B,L,C]
    __bf16* Op1 = Op0 + n;                // O-half 1
    float*  Ls  = (float*)(Op1 + n);      // [2][B*NH][L] exp-sums

    proj_mfma_kernel<<<dim3(L_DIM/128, 6, B_DIM), 256, 0, stream>>>(
        x, Wq, Wk, Wv, Qb, Kb, Vb);
    attn_kernel<<<dim3(L_DIM/256, NH, B_DIM * 2), 256, 0, stream>>>(
        Qb, Kb, Vb, Op0, Op1, Ls);
    final_mfma_kernel<<<dim3(L_DIM/64, 2, B_DIM), 256, 0, stream>>>(
        Op0, Op1, Ls, Wl, y);
}

// Round 11
// 205.448 us; speedup vs baseline: 1.0117x; 1.0022x over previous
//
#include <hip/hip_runtime.h>

#define L_DIM 4096
#define C_DIM 256
#define B_DIM 4
#define NH 8
#define DK 32

// Folds softmax 1/sqrt(DK) AND log2(e) into Wq at staging time, so the
// attention kernel uses a single v_exp_f32 (exp2) per score.
#define QSCALE 0.25507694f   // (1/sqrt(32)) * log2(e)

typedef __bf16 bf16x8 __attribute__((ext_vector_type(8)));
typedef float  f32x4  __attribute__((ext_vector_type(4)));
typedef float  f32x8  __attribute__((ext_vector_type(8)));
typedef float  f32x16 __attribute__((ext_vector_type(16)));

// pack two f32 -> packed bf16 pair (round-to-nearest via +0x8000, then
// byte-perm). Correct nearest-rounding for finite sign-magnitude values.
static __device__ __forceinline__ unsigned pk_bf16(float lo, float hi) {
    unsigned a = __builtin_bit_cast(unsigned, lo) + 0x8000u;
    unsigned b = __builtin_bit_cast(unsigned, hi) + 0x8000u;
    return __builtin_amdgcn_perm(b, a, 0x07060302u);   // {b[31:16], a[31:16]}
}

// ---------------------------------------------------------------------------
// Kernel 1: Q/K/V projections as bf16 MFMA GEMM, x-transpose fused into
// staging (R10 version — best measured).
// ---------------------------------------------------------------------------
__global__ __launch_bounds__(256) void proj_mfma_kernel(
    const float* __restrict__ x, const float* __restrict__ Wq,
    const float* __restrict__ Wk, const float* __restrict__ Wv,
    __bf16* __restrict__ Qb, __bf16* __restrict__ Kb, __bf16* __restrict__ Vb)
{
    const int t    = threadIdx.x;
    const int wave = t >> 6;
    const int lane = t & 63;
    const int n32  = lane & 31;
    const int hl   = lane >> 5;
    const int l0   = blockIdx.x * 128;
    const int ob   = blockIdx.y & 1;
    const int p    = blockIdx.y >> 1;   // 0=Q 1=K 2=V
    const int b    = blockIdx.z;
    const float* W = (p == 0) ? Wq : ((p == 1) ? Wk : Wv);
    const float sc = (p == 0) ? QSCALE : 1.0f;

    __shared__ __attribute__((aligned(16))) __bf16 Wt[128][72];  // [o][c]
    __shared__ __attribute__((aligned(16))) __bf16 Xs[128][72];  // [l][c] swz

    const int wo  = t >> 1, wcc = (t & 1) * 32;
    const float* wg = W + (size_t)(ob * 128 + wo) * C_DIM + wcc;

    // x-stage geometry: thread covers c = bk*64 + cg*4 .. +3, l = lq*8 .. +7
    const int lq  = t & 15;
    const int cg  = t >> 4;
    const int swW = (lq & 7) * 8;   // write swizzle: rows lq*8+j have row>>3 == lq
    const float* xg = x + ((size_t)b * C_DIM + cg * 4) * L_DIM + l0 + lq * 8;

    const int moff = (wave & 1) * 64;
    const int noff = (wave >> 1) * 64;
    const int sw0  = ((n32 >> 3) & 7) * 8;        // read swizzle, rows noff+n32
    const int sw1  = ((4 + (n32 >> 3)) & 7) * 8;  // rows noff+32+n32

    f32x16 acc[2][2];
    #pragma unroll
    for (int i = 0; i < 2; ++i)
        #pragma unroll
        for (int j = 0; j < 2; ++j)
            #pragma unroll
            for (int r = 0; r < 16; ++r) acc[i][j][r] = 0.f;

    unsigned wpk[16];
    unsigned ux[16];

#define XSTAGE_LOAD(bkk)                                                      \
    {                                                                         \
        const float* xp = xg + (size_t)(bkk) * 64 * L_DIM;                    \
        f32x8 r0 = *(const f32x8*)(xp);                                       \
        f32x8 r1 = *(const f32x8*)(xp + L_DIM);                               \
        _Pragma("unroll")                                                     \
        for (int j = 0; j < 8; ++j) ux[j] = pk_bf16(r0[j], r1[j]);            \
        f32x8 r2 = *(const f32x8*)(xp + 2 * L_DIM);                           \
        f32x8 r3 = *(const f32x8*)(xp + 3 * L_DIM);                           \
        _Pragma("unroll")                                                     \
        for (int j = 0; j < 8; ++j) ux[8 + j] = pk_bf16(r2[j], r3[j]);        \
    }

    #pragma unroll
    for (int k = 0; k < 8; ++k) {
        f32x4 wv = *(const f32x4*)(wg + k * 4);
        wpk[k * 2]     = pk_bf16(wv[0] * sc, wv[1] * sc);
        wpk[k * 2 + 1] = pk_bf16(wv[2] * sc, wv[3] * sc);
    }
    XSTAGE_LOAD(0)

    for (int bk = 0; bk < 4; ++bk) {
        __syncthreads();
        #pragma unroll
        for (int g = 0; g < 4; ++g)
            *(uint4*)&Wt[wo][wcc + g * 8] =
                make_uint4(wpk[g*4], wpk[g*4+1], wpk[g*4+2], wpk[g*4+3]);
        #pragma unroll
        for (int j = 0; j < 8; ++j)
            *(uint2*)&Xs[lq * 8 + j][(cg * 4) ^ swW] = make_uint2(ux[j], ux[8 + j]);
        if (bk < 3) {
            #pragma unroll
            for (int k = 0; k < 8; ++k) {
                f32x4 wv = *(const f32x4*)(wg + (bk + 1) * 64 + k * 4);
                wpk[k * 2]     = pk_bf16(wv[0] * sc, wv[1] * sc);
                wpk[k * 2 + 1] = pk_bf16(wv[2] * sc, wv[3] * sc);
            }
            XSTAGE_LOAD(bk + 1)
        }
        __syncthreads();

        #pragma unroll
        for (int ks = 0; ks < 4; ++ks) {
            bf16x8 a0 = *(const bf16x8*)&Wt[moff + n32     ][ks * 16 + hl * 8];
            bf16x8 a1 = *(const bf16x8*)&Wt[moff + 32 + n32][ks * 16 + hl * 8];
            bf16x8 b0 = *(const bf16x8*)&Xs[noff + n32     ][(ks * 16 + hl * 8) ^ sw0];
            bf16x8 b1 = *(const bf16x8*)&Xs[noff + 32 + n32][(ks * 16 + hl * 8) ^ sw1];
            acc[0][0] = __builtin_amdgcn_mfma_f32_32x32x16_bf16(a0, b0, acc[0][0], 0, 0, 0);
            acc[0][1] = __builtin_amdgcn_mfma_f32_32x32x16_bf16(a0, b1, acc[0][1], 0, 0, 0);
            acc[1][0] = __builtin_amdgcn_mfma_f32_32x32x16_bf16(a1, b0, acc[1][0], 0, 0, 0);
            acc[1][1] = __builtin_amdgcn_mfma_f32_32x32x16_bf16(a1, b1, acc[1][1], 0, 0, 0);
        }
    }
#undef XSTAGE_LOAD

    #pragma unroll
    for (int mt = 0; mt < 2; ++mt) {
        const int o32 = ob * 128 + moff + mt * 32;
        const int h   = o32 >> 5;
        const int bh  = b * NH + h;
        #pragma unroll
        for (int nt = 0; nt < 2; ++nt) {
            const int l = l0 + noff + nt * 32 + n32;
            if (p < 2) {
                __bf16* out = ((p == 0) ? Qb : Kb) + ((size_t)bh * L_DIM + l) * DK;
                #pragma unroll
                for (int g = 0; g < 4; ++g) {
                    unsigned u0 = pk_bf16(acc[mt][nt][g*4],     acc[mt][nt][g*4+1]);
                    unsigned u1 = pk_bf16(acc[mt][nt][g*4+2],   acc[mt][nt][g*4+3]);
                    *(uint2*)(out + 4 * hl + 8 * g) = make_uint2(u0, u1);
                }
            } else {
                #pragma unroll
                for (int r = 0; r < 16; ++r) {
                    const int dk = (r & 3) + 4 * hl + 8 * (r >> 2);
                    Vb[((size_t)bh * DK + dk) * L_DIM + l] = (__bf16)acc[mt][nt][r];
                }
            }
        }
    }
}

// ---------------------------------------------------------------------------
// Kernel 2: flash attention, K-SPLIT x2, KVBLK=128, double-buffered LDS,
// T14 async-STAGE split, lacc on the MFMA pipe (R8/R10 attn). Change this
// round: T1 XCD-aware stream remap. Default linear->XCD round-robin (p%8)
// spreads the 16 q-blocks of one (bh,khalf) KV stream across all 8 XCDs,
// so every XCD L2 re-fetches every stream (FETCH 73.8 MB vs ~30 ideal).
// Bijective remap p -> (c=p&7, xq=(p>>3)&15, g=p>>7), str=c*8+g: all 16
// q-blocks of a stream share XCD c; each XCD serves the 8 heads of one
// (b,khalf) = 2 MB KV, fitting its 4 MB L2. Math untouched.
// ---------------------------------------------------------------------------
#define SCORE_TILE(K0, K1, V0, V1)                                            \
    _Pragma("unroll")                                                         \
    for (int qt = 0; qt < 2; ++qt) {                                          \
        f32x16 s = __builtin_amdgcn_mfma_f32_32x32x16_bf16(                   \
            K0, qf[qt][0], z16, 0, 0, 0);                                     \
        s = __builtin_amdgcn_mfma_f32_32x32x16_bf16(K1, qf[qt][1], s, 0, 0, 0); \
        f32x8 e0, e1;                                                         \
        _Pragma("unroll")                                                     \
        for (int r = 0; r < 8; ++r) {                                         \
            e0[r] = __builtin_amdgcn_exp2f(s[r]);                             \
            e1[r] = __builtin_amdgcn_exp2f(s[8 + r]);                         \
        }                                                                     \
        bf16x8 p0 = __builtin_convertvector(e0, bf16x8);                      \
        bf16x8 p1 = __builtin_convertvector(e1, bf16x8);                      \
        oacc[qt] = __builtin_amdgcn_mfma_f32_32x32x16_bf16(                   \
            V0, p0, oacc[qt], 0, 0, 0);                                       \
        lacc[qt] = __builtin_amdgcn_mfma_f32_32x32x16_bf16(                   \
            ones, p0, lacc[qt], 0, 0, 0);                                     \
        oacc[qt] = __builtin_amdgcn_mfma_f32_32x32x16_bf16(                   \
            V1, p1, oacc[qt], 0, 0, 0);                                       \
        lacc[qt] = __builtin_amdgcn_mfma_f32_32x32x16_bf16(                   \
            ones, p1, lacc[qt], 0, 0, 0);                                     \
    }

__global__ __launch_bounds__(256) void attn_kernel(
    const __bf16* __restrict__ Q, const __bf16* __restrict__ K,
    const __bf16* __restrict__ V, __bf16* __restrict__ Op0,
    __bf16* __restrict__ Op1, float* __restrict__ Ls)
{
    const int tid   = threadIdx.x;
    const int lane  = tid & 63;
    const int n32   = lane & 31;
    const int hl    = lane >> 5;
    const int wave  = tid >> 6;

    // T1 XCD-aware bijective remap (grid 16x8x8 -> p in [0,1024))
    const int p_    = blockIdx.x + 16 * (blockIdx.y + 8 * blockIdx.z);
    const int c_    = p_ & 7;            // XCD (round-robin on linear id)
    const int xq    = (p_ >> 3) & 15;    // q-tile within stream
    const int g_    = p_ >> 7;           // head within XCD's stream group
    const int str   = c_ * 8 + g_;       // stream id in [0,64)
    const int h     = str & 7;
    const int zz    = str >> 3;
    const int b     = zz >> 1;
    const int khalf = zz & 1;
    const int bh    = b * NH + h;
    const int q0    = xq * 256 + wave * 64;

    __shared__ __attribute__((aligned(16))) __bf16 Ks[2][128][40];
    __shared__ __attribute__((aligned(16))) __bf16 Vs[2][32][136];

    bf16x8 qf[2][2];
    #pragma unroll
    for (int qt = 0; qt < 2; ++qt) {
        const __bf16* qp = Q + ((size_t)bh * L_DIM + q0 + qt * 32 + n32) * DK;
        qf[qt][0] = *(const bf16x8*)(qp + hl * 8);
        qf[qt][1] = *(const bf16x8*)(qp + 16 + hl * 8);
    }

    f32x16 oacc[2], lacc[2];
    #pragma unroll
    for (int qt = 0; qt < 2; ++qt)
        #pragma unroll
        for (int r = 0; r < 16; ++r) { oacc[qt][r] = 0.f; lacc[qt][r] = 0.f; }

    const f32x16 z16 = {};

    bf16x8 ones;
    #pragma unroll
    for (int j = 0; j < 8; ++j) ones[j] = (__bf16)1.0f;

    // staging addresses: 128 kpos/tile, 32B (2x bf16x8) per thread.
    const __bf16* kg = K + (size_t)bh * L_DIM * DK + (size_t)khalf * 2048 * DK
                         + (tid >> 1) * DK + (tid & 1) * 16;
    const __bf16* vg = V + ((size_t)bh * DK + (tid >> 3)) * L_DIM
                         + khalf * 2048 + (tid & 7) * 16;
    const int kr = tid >> 1, kc = (tid & 1) * 16;
    const int j16 = (tid & 7) * 16;   // V dest group base col
    const int vr  = tid >> 3;

    // prologue: stage tile 0 into buf0, prefetch tile 1 into regs
    bf16x8 kreg0 = *(const bf16x8*)(kg);
    bf16x8 kreg1 = *(const bf16x8*)(kg + 8);
    bf16x8 vreg0 = *(const bf16x8*)(vg);
    bf16x8 vreg1 = *(const bf16x8*)(vg + 8);
    {
        *(bf16x8*)&Ks[0][kr][kc]     = kreg0;
        *(bf16x8*)&Ks[0][kr][kc + 8] = kreg1;
        union { bf16x8 v; uint2 u2[2]; } v0, v1;
        v0.v = vreg0; v1.v = vreg1;
        *(uint2*)&Vs[0][vr][j16]      = v0.u2[0];   // kpos g 0-3
        *(uint2*)&Vs[0][vr][j16 + 8]  = v0.u2[1];   // kpos g 4-7
        *(uint2*)&Vs[0][vr][j16 + 4]  = v1.u2[0];   // kpos g 8-11
        *(uint2*)&Vs[0][vr][j16 + 12] = v1.u2[1];   // kpos g 12-15
    }
    kreg0 = *(const bf16x8*)(kg + (size_t)1 * 128 * DK);
    kreg1 = *(const bf16x8*)(kg + (size_t)1 * 128 * DK + 8);
    vreg0 = *(const bf16x8*)(vg + 128);
    vreg1 = *(const bf16x8*)(vg + 128 + 8);

    #pragma unroll 2
    for (int kt = 0; kt < 16; ++kt) {
        const int cur = kt & 1;
        __syncthreads();   // buf[cur] (tile kt) staged; prior reads of buf[cur^1] done

        // ---- first half fragments (mt 0,1) ----
        bf16x8 kA0 = *(const bf16x8*)&Ks[cur][n32     ][hl * 8];
        bf16x8 kA1 = *(const bf16x8*)&Ks[cur][n32     ][16 + hl * 8];
        bf16x8 kB0 = *(const bf16x8*)&Ks[cur][32 + n32][hl * 8];
        bf16x8 kB1 = *(const bf16x8*)&Ks[cur][32 + n32][16 + hl * 8];
        bf16x8 vA0 = *(const bf16x8*)&Vs[cur][n32][     hl * 8];
        bf16x8 vA1 = *(const bf16x8*)&Vs[cur][n32][16 + hl * 8];
        bf16x8 vB0 = *(const bf16x8*)&Vs[cur][n32][32 + hl * 8];
        bf16x8 vB1 = *(const bf16x8*)&Vs[cur][n32][48 + hl * 8];

        __builtin_amdgcn_s_setprio(1);
        SCORE_TILE(kA0, kA1, vA0, vA1)   // mt=0
        SCORE_TILE(kB0, kB1, vB0, vB1)   // mt=1
        __builtin_amdgcn_s_setprio(0);

        // ---- second half fragments (mt 2,3) — read BEFORE writes so the
        // second compute half waits only on these reads (LDS FIFO) ----
        kA0 = *(const bf16x8*)&Ks[cur][64 + n32][hl * 8];
        kA1 = *(const bf16x8*)&Ks[cur][64 + n32][16 + hl * 8];
        kB0 = *(const bf16x8*)&Ks[cur][96 + n32][hl * 8];
        kB1 = *(const bf16x8*)&Ks[cur][96 + n32][16 + hl * 8];
        vA0 = *(const bf16x8*)&Vs[cur][n32][64 + hl * 8];
        vA1 = *(const bf16x8*)&Vs[cur][n32][80 + hl * 8];
        vB0 = *(const bf16x8*)&Vs[cur][n32][96 + hl * 8];
        vB1 = *(const bf16x8*)&Vs[cur][n32][112 + hl * 8];

        if (kt < 15) {
            // T14: write tile kt+1 into the other buffer NOW (drains under
            // the second compute half), then issue depth-2 prefetch.
            *(bf16x8*)&Ks[cur ^ 1][kr][kc]     = kreg0;
            *(bf16x8*)&Ks[cur ^ 1][kr][kc + 8] = kreg1;
            union { bf16x8 v; uint2 u2[2]; } v0, v1;
            v0.v = vreg0; v1.v = vreg1;
            *(uint2*)&Vs[cur ^ 1][vr][j16]      = v0.u2[0];
            *(uint2*)&Vs[cur ^ 1][vr][j16 + 8]  = v0.u2[1];
            *(uint2*)&Vs[cur ^ 1][vr][j16 + 4]  = v1.u2[0];
            *(uint2*)&Vs[cur ^ 1][vr][j16 + 12] = v1.u2[1];
            const int nkt = (kt + 2) & 15;   // wraps, discarded at end
            kreg0 = *(const bf16x8*)(kg + (size_t)nkt * 128 * DK);
            kreg1 = *(const bf16x8*)(kg + (size_t)nkt * 128 * DK + 8);
            vreg0 = *(const bf16x8*)(vg + nkt * 128);
            vreg1 = *(const bf16x8*)(vg + nkt * 128 + 8);
        }

        __builtin_amdgcn_s_setprio(1);
        SCORE_TILE(kA0, kA1, vA0, vA1)   // mt=2
        SCORE_TILE(kB0, kB1, vB0, vB1)   // mt=3
        __builtin_amdgcn_s_setprio(0);
    }

    // epilogue: unnormalized O-half -> Op[khalf] in [B,L,C] layout; lsum -> Ls
    __bf16* Op = khalf ? Op1 : Op0;
    #pragma unroll
    for (int qt = 0; qt < 2; ++qt) {
        const int l = q0 + qt * 32 + n32;
        __bf16* ap = Op + ((size_t)b * L_DIM + l) * C_DIM + h * 32 + 4 * hl;
        #pragma unroll
        for (int g = 0; g < 4; ++g) {
            *(uint2*)(ap + 8 * g) = make_uint2(
                pk_bf16(oacc[qt][g*4],     oacc[qt][g*4+1]),
                pk_bf16(oacc[qt][g*4+2],   oacc[qt][g*4+3]));
        }
        Ls[((size_t)khalf * B_DIM * NH + bh) * L_DIM + l] = lacc[qt][0];
    }
}

// ---------------------------------------------------------------------------
// Kernel 3: final projection as bf16 MFMA GEMM with the K-split combine
// fused into staging: at = relu((O1+O2)/(l1+l2)).
// ---------------------------------------------------------------------------
__global__ __launch_bounds__(256) void final_mfma_kernel(
    const __bf16* __restrict__ Op0, const __bf16* __restrict__ Op1,
    const float* __restrict__ Ls, const float* __restrict__ Wl,
    float* __restrict__ y)
{
    const int t    = threadIdx.x;
    const int wave = t >> 6;
    const int lane = t & 63;
    const int n32  = lane & 31;
    const int hl   = lane >> 5;
    const int l0   = blockIdx.x * 64;
    const int ob   = blockIdx.y;
    const int b    = blockIdx.z;

    __shared__ __attribute__((aligned(16))) __bf16 Wt[128][72];
    __shared__ __attribute__((aligned(16))) __bf16 Xs[64][72];

    const int wo  = t >> 1, wcc = (t & 1) * 32;
    const int xl  = t >> 2, xcc = (t & 3) * 16;
    const float* wg = Wl + (size_t)(ob * 128 + wo) * C_DIM + wcc;
    const size_t obase = ((size_t)b * L_DIM + l0 + xl) * C_DIM + xcc;

    // per-bk inverse denominators: head for chunk bk is bk*2 + (xcc>>5 within 64)
    float inv[4];
    {
        const int lidx = l0 + xl;
        #pragma unroll
        for (int bk = 0; bk < 4; ++bk) {
            const int hh = (bk * 64 + xcc) >> 5;
            const float l1 = Ls[((size_t)0 * B_DIM * NH + b * NH + hh) * L_DIM + lidx];
            const float l2 = Ls[((size_t)1 * B_DIM * NH + b * NH + hh) * L_DIM + lidx];
            inv[bk] = __builtin_amdgcn_rcpf(l1 + l2);
        }
    }

    const int moff = (wave & 1) * 64;
    const int noff = (wave >> 1) * 32;

    f32x16 acc[2];
    #pragma unroll
    for (int i = 0; i < 2; ++i)
        #pragma unroll
        for (int r = 0; r < 16; ++r) acc[i][r] = 0.f;

    unsigned wpk[16];
    bf16x8   o1r, o2r;
    #pragma unroll
    for (int k = 0; k < 8; ++k) {
        f32x4 wv = *(const f32x4*)(wg + k * 4);
        wpk[k * 2]     = pk_bf16(wv[0], wv[1]);
        wpk[k * 2 + 1] = pk_bf16(wv[2], wv[3]);
    }
    o1r = *(const bf16x8*)(Op0 + obase);
    o2r = *(const bf16x8*)(Op1 + obase);
    bf16x8 o1r2 = *(const bf16x8*)(Op0 + obase + 8);
    bf16x8 o2r2 = *(const bf16x8*)(Op1 + obase + 8);

    for (int bk = 0; bk < 4; ++bk) {
        __syncthreads();
        #pragma unroll
        for (int g = 0; g < 4; ++g)
            *(uint4*)&Wt[wo][wcc + g * 8] =
                make_uint4(wpk[g*4], wpk[g*4+1], wpk[g*4+2], wpk[g*4+3]);
        {   // combine halves: relu((O1+O2)*inv) -> bf16 fragment row
            unsigned u[4];
            #pragma unroll
            for (int i = 0; i < 4; ++i) {
                float v0 = ((float)o1r[2*i]   + (float)o2r[2*i]  ) * inv[bk];
                float v1 = ((float)o1r[2*i+1] + (float)o2r[2*i+1]) * inv[bk];
                v0 = v0 > 0.f ? v0 : 0.f;
                v1 = v1 > 0.f ? v1 : 0.f;
                u[i] = pk_bf16(v0, v1);
            }
            *(uint4*)&Xs[xl][xcc] = make_uint4(u[0], u[1], u[2], u[3]);
            #pragma unroll
            for (int i = 0; i < 4; ++i) {
                float v0 = ((float)o1r2[2*i]   + (float)o2r2[2*i]  ) * inv[bk];
                float v1 = ((float)o1r2[2*i+1] + (float)o2r2[2*i+1]) * inv[bk];
                v0 = v0 > 0.f ? v0 : 0.f;
                v1 = v1 > 0.f ? v1 : 0.f;
                u[i] = pk_bf16(v0, v1);
            }
            *(uint4*)&Xs[xl][xcc + 8] = make_uint4(u[0], u[1], u[2], u[3]);
        }
        if (bk < 3) {
            #pragma unroll
            for (int k = 0; k < 8; ++k) {
                f32x4 wv = *(const f32x4*)(wg + (bk + 1) * 64 + k * 4);
                wpk[k * 2]     = pk_bf16(wv[0], wv[1]);
                wpk[k * 2 + 1] = pk_bf16(wv[2], wv[3]);
            }
            o1r  = *(const bf16x8*)(Op0 + obase + (bk + 1) * 64);
            o2r  = *(const bf16x8*)(Op1 + obase + (bk + 1) * 64);
            o1r2 = *(const bf16x8*)(Op0 + obase + (bk + 1) * 64 + 8);
            o2r2 = *(const bf16x8*)(Op1 + obase + (bk + 1) * 64 + 8);
        }
        __syncthreads();

        #pragma unroll
        for (int ks = 0; ks < 4; ++ks) {
            bf16x8 a0 = *(const bf16x8*)&Wt[moff + n32     ][ks * 16 + hl * 8];
            bf16x8 a1 = *(const bf16x8*)&Wt[moff + 32 + n32][ks * 16 + hl * 8];
            bf16x8 b0 = *(const bf16x8*)&Xs[noff + n32     ][ks * 16 + hl * 8];
            acc[0] = __builtin_amdgcn_mfma_f32_32x32x16_bf16(a0, b0, acc[0], 0, 0, 0);
            acc[1] = __builtin_amdgcn_mfma_f32_32x32x16_bf16(a1, b0, acc[1], 0, 0, 0);
        }
    }

    #pragma unroll
    for (int mt = 0; mt < 2; ++mt) {
        #pragma unroll
        for (int r = 0; r < 16; ++r) {
            const int o = ob * 128 + moff + mt * 32 + (r & 3) + 4 * hl + 8 * (r >> 2);
            y[((size_t)b * C_DIM + o) * L_DIM + l0 + noff + n32] = acc[mt][r];
        }
    }
}

// ---------------------------------------------------------------------------
extern "C" void kernel_launch(void* const* d_in, const int* in_sizes, int n_in,
                              void* d_out, int out_size, void* d_ws, size_t ws_size,
                              hipStream_t stream)
{
    const float* x  = (const float*)d_in[0];
    const float* Wq = (const float*)d_in[1];
    const float* Wk = (const float*)d_in[2];
    const float* Wv = (const float*)d_in[3];
    const float* Wl = (const float*)d_in[4];
    float* y = (float*)d_out;

    const size_t n = (size_t)B_DIM * NH * L_DIM * DK;   // 4,194,304 elems
    __bf16* Qb  = (__bf16*)d_ws;          // [B,H,L,DK]
    __bf16* Kb  = Qb + n;
    __bf16* Vb  = Kb + n;                 // [B,H,DK,L]
    __bf16* Op0 = Vb + n;                 // O-half 0, [B,L,C]
    __bf16* Op1 = Op0 + n;                // O-half 1
    float*  Ls  = (float*)(Op1 + n);      // [2][B*NH][L] exp-sums

    proj_mfma_kernel<<<dim3(L_DIM/128, 6, B_DIM), 256, 0, stream>>>(
        x, Wq, Wk, Wv, Qb, Kb, Vb);
    attn_kernel<<<dim3(L_DIM/256, NH, B_DIM * 2), 256, 0, stream>>>(
        Qb, Kb, Vb, Op0, Op1, Ls);
    final_mfma_kernel<<<dim3(L_DIM/64, 2, B_DIM), 256, 0, stream>>>(
        Op0, Op1, Ls, Wl, y);
}